// Round 1
// baseline (1617.604 us; speedup 1.0000x reference)
//
#include <hip/hip_runtime.h>
#include <math.h>

#define ND 64
constexpr int SCAN_BLK = 1024;

__device__ __forceinline__ float sigmoidf_(float x){ return 1.f/(1.f+__expf(-x)); }

// ---------------- CSR build ----------------
__global__ void k_degree(const int* __restrict__ col, int* __restrict__ deg, int E){
  int i = blockIdx.x*blockDim.x + threadIdx.x;
  if (i < E) atomicAdd(&deg[col[i]], 1);
}

__global__ void k_dinv(const int* __restrict__ deg, float* __restrict__ dinv, int N){
  int i = blockIdx.x*blockDim.x + threadIdx.x;
  if (i < N) dinv[i] = rsqrtf((float)(deg[i] + 1));   // +1 = self loop
}

__global__ void k_scan1(const int* __restrict__ cnt, int* __restrict__ partial,
                        int* __restrict__ bsum, int n){
  __shared__ int tmp[SCAN_BLK];
  int i = blockIdx.x*SCAN_BLK + threadIdx.x;
  int v = (i<n) ? cnt[i] : 0;
  tmp[threadIdx.x] = v; __syncthreads();
  for (int off=1; off<SCAN_BLK; off<<=1){
    int t = (threadIdx.x>=off) ? tmp[threadIdx.x-off] : 0;
    __syncthreads();
    tmp[threadIdx.x] += t;
    __syncthreads();
  }
  if (i<n) partial[i] = tmp[threadIdx.x];
  if (threadIdx.x==SCAN_BLK-1) bsum[blockIdx.x] = tmp[threadIdx.x];
}

__global__ void k_scan2(int* bsum, int nb){
  if (threadIdx.x==0 && blockIdx.x==0){
    int acc=0;
    for (int b=0;b<nb;b++){ int v=bsum[b]; bsum[b]=acc; acc+=v; }
  }
}

__global__ void k_scan3(const int* __restrict__ partial, const int* __restrict__ bsum,
                        int* __restrict__ rowptr, int n){
  int i = blockIdx.x*SCAN_BLK + threadIdx.x;
  if (i<n){
    rowptr[i+1] = partial[i] + bsum[blockIdx.x];
    if (i==0) rowptr[0] = 0;
  }
}

__global__ void k_fill(const int* __restrict__ row, const int* __restrict__ col,
                       const int* __restrict__ rowptr, int* __restrict__ fill,
                       int* __restrict__ csr, int E){
  int i = blockIdx.x*blockDim.x + threadIdx.x;
  if (i < E){
    int c = col[i];
    int pos = rowptr[c] + atomicAdd(&fill[c], 1);
    csr[pos] = row[i];
  }
}

// ---------------- input MLP: out = relu(x @ W0 + b0) ----------------
__global__ void k_input(const float* __restrict__ x, const float* __restrict__ W0,
                        const float* __restrict__ b0, float* __restrict__ out, int N){
  __shared__ float w0s[15*ND];
  __shared__ float b0s[ND];
  int tid = threadIdx.x;
  for (int i=tid; i<15*ND; i+=256) w0s[i] = W0[i];
  if (tid < ND) b0s[tid] = b0[tid];
  __syncthreads();
  int node = blockIdx.x*4 + (tid>>6);
  int f = tid & 63;
  if (node < N){
    float acc = b0s[f];
    const float* xr = x + (size_t)node*15;
    #pragma unroll
    for (int k=0;k<15;k++) acc += xr[k]*w0s[k*ND+f];
    out[(size_t)node*ND+f] = fmaxf(acc, 0.f);
  }
}

// ---------------- g = dinv * (out @ Wc) ----------------
__global__ void k_transform(const float* __restrict__ out, const float* __restrict__ Wc,
                            const float* __restrict__ dinv, float* __restrict__ g, int N){
  __shared__ float wcs[ND*ND];
  __shared__ float xs[16][ND];
  int tid = threadIdx.x;
  for (int i=tid; i<ND*ND; i+=256) wcs[i] = Wc[i];
  int nb = blockIdx.x*16;
  for (int i=tid; i<16*ND; i+=256){
    int n = i>>6, k = i&63; int node = nb+n;
    xs[n][k] = (node<N) ? out[(size_t)node*ND+k] : 0.f;
  }
  __syncthreads();
  int f = tid&63, nq = tid>>6;
  float acc0=0.f, acc1=0.f, acc2=0.f, acc3=0.f;
  #pragma unroll 16
  for (int k=0;k<ND;k++){
    float w = wcs[k*ND+f];
    acc0 += w*xs[nq*4+0][k];
    acc1 += w*xs[nq*4+1][k];
    acc2 += w*xs[nq*4+2][k];
    acc3 += w*xs[nq*4+3][k];
  }
  int n0 = nb + nq*4;
  if (n0+0 < N) g[(size_t)(n0+0)*ND+f] = dinv[n0+0]*acc0;
  if (n0+1 < N) g[(size_t)(n0+1)*ND+f] = dinv[n0+1]*acc1;
  if (n0+2 < N) g[(size_t)(n0+2)*ND+f] = dinv[n0+2]*acc2;
  if (n0+3 < N) g[(size_t)(n0+3)*ND+f] = dinv[n0+3]*acc3;
}

// ---------------- out[dst] = relu(dinv[dst]*(sum g[src] + g[dst]) + bc) ----------------
__global__ void k_gather(const float* __restrict__ g, const int* __restrict__ rowptr,
                         const int* __restrict__ csr, const float* __restrict__ dinv,
                         const float* __restrict__ bc, float* __restrict__ out, int N){
  int tid = threadIdx.x;
  int node = blockIdx.x*4 + (tid>>6);
  if (node >= N) return;
  int lane = tid & 63;
  int s = rowptr[node], e = rowptr[node+1];
  float a0 = g[(size_t)node*ND+lane];   // self loop
  float a1=0.f, a2=0.f, a3=0.f;
  int i = s;
  for (; i+4 <= e; i += 4){
    int s0=csr[i], s1=csr[i+1], s2=csr[i+2], s3=csr[i+3];
    a0 += g[(size_t)s0*ND+lane];
    a1 += g[(size_t)s1*ND+lane];
    a2 += g[(size_t)s2*ND+lane];
    a3 += g[(size_t)s3*ND+lane];
  }
  for (; i<e; ++i) a0 += g[(size_t)csr[i]*ND+lane];
  float r = dinv[node]*((a0+a1)+(a2+a3)) + bc[lane];
  out[(size_t)node*ND+lane] = fmaxf(r, 0.f);
}

// ---------------- per-graph contiguous ranges (batch is sorted) ----------------
__global__ void k_goff(const int* __restrict__ batch, int* __restrict__ goff, int N, int B){
  int i = blockIdx.x*blockDim.x + threadIdx.x;
  if (i >= N) return;
  int b = batch[i];
  if (i == 0){ for (int g2=0; g2<=b; ++g2) goff[g2]=0; }
  else {
    int bp = batch[i-1];
    for (int g2=bp+1; g2<=b; ++g2) goff[g2]=i;
  }
  if (i == N-1){ for (int g2=b+1; g2<=B; ++g2) goff[g2]=N; }
}

// ---------------- LSTM step (8 graphs per block) ----------------
__global__ void k_lstm(const float* __restrict__ Wih, const float* __restrict__ Whh,
                       const float* __restrict__ bih, const float* __restrict__ bhh,
                       float* __restrict__ qs, float* __restrict__ hl, float* __restrict__ cl){
  __shared__ float qsr[8][128];
  __shared__ float hlr[8][64];
  __shared__ float gat[8][256];
  int tid = threadIdx.x;
  int g0 = blockIdx.x*8;
  for (int i=tid; i<8*128; i+=256){ int gg=i>>7, k=i&127; qsr[gg][k] = qs[(size_t)(g0+gg)*128+k]; }
  for (int i=tid; i<8*64;  i+=256){ int gg=i>>6, k=i&63;  hlr[gg][k] = hl[(size_t)(g0+gg)*64+k]; }
  __syncthreads();
  int j = tid;  // gate index 0..255
  float bb = bih[j] + bhh[j];
  float acc[8];
  #pragma unroll
  for (int gg=0; gg<8; gg++) acc[gg] = bb;
  const float* wr = Wih + (size_t)j*128;
  for (int k=0; k<128; k++){
    float w = wr[k];
    #pragma unroll
    for (int gg=0; gg<8; gg++) acc[gg] += w*qsr[gg][k];
  }
  const float* wr2 = Whh + (size_t)j*64;
  for (int k=0; k<64; k++){
    float w = wr2[k];
    #pragma unroll
    for (int gg=0; gg<8; gg++) acc[gg] += w*hlr[gg][k];
  }
  #pragma unroll
  for (int gg=0; gg<8; gg++) gat[gg][j] = acc[gg];
  __syncthreads();
  #pragma unroll
  for (int it=0; it<2; ++it){
    int idx = it*256 + tid;
    int gg = idx>>6, d = idx&63;
    int graph = g0+gg;
    float ig = sigmoidf_(gat[gg][d]);
    float fg = sigmoidf_(gat[gg][64+d]);
    float gv = tanhf(gat[gg][128+d]);
    float og = sigmoidf_(gat[gg][192+d]);
    float c = fg*cl[(size_t)graph*64+d] + ig*gv;
    float h = og*tanhf(c);
    cl[(size_t)graph*64+d] = c;
    hl[(size_t)graph*64+d] = h;
    qs[(size_t)graph*128+d] = h;   // q part of q_star
  }
}

// ---------------- attention pooling, block per graph ----------------
__global__ void k_attn(const float* __restrict__ out, const int* __restrict__ goff,
                       const float* __restrict__ hl, float* __restrict__ qs){
  __shared__ float redw[4];
  __shared__ float redr[4][64];
  int g = blockIdx.x;
  int tid = threadIdx.x, lane = tid&63, wv = tid>>6;
  int s = goff[g], e = goff[g+1];
  float q = hl[(size_t)g*64+lane];
  // pass A: global max of e_n = dot(out[n], q)
  float mx = -1e30f;
  for (int n=s+wv; n<e; n+=4){
    float p = out[(size_t)n*64+lane]*q;
    #pragma unroll
    for (int off=32; off>=1; off>>=1) p += __shfl_xor(p, off, 64);
    mx = fmaxf(mx, p);
  }
  if (lane==0) redw[wv] = mx;
  __syncthreads();
  float m = fmaxf(fmaxf(redw[0],redw[1]), fmaxf(redw[2],redw[3]));
  __syncthreads();
  // pass B: denom and weighted sum in one sweep
  float denom=0.f, racc=0.f;
  for (int n=s+wv; n<e; n+=4){
    float v = out[(size_t)n*64+lane];
    float p = v*q;
    #pragma unroll
    for (int off=32; off>=1; off>>=1) p += __shfl_xor(p, off, 64);
    float w = __expf(p - m);
    denom += w;
    racc += w*v;
  }
  if (lane==0) redw[wv] = denom;
  redr[wv][lane] = racc;
  __syncthreads();
  if (wv==0){
    float dtot = redw[0]+redw[1]+redw[2]+redw[3];
    float rs = redr[0][lane]+redr[1][lane]+redr[2][lane]+redr[3][lane];
    qs[(size_t)g*128+64+lane] = (dtot > 0.f) ? rs/dtot : 0.f;
  }
}

// ---------------- final MLP ----------------
__global__ void k_final(const float* __restrict__ qs, const float* __restrict__ W1,
                        const float* __restrict__ b1, const float* __restrict__ W2,
                        const float* __restrict__ b2, float* __restrict__ outy){
  __shared__ float qsr[128];
  __shared__ float yy[64];
  int g = blockIdx.x; int t = threadIdx.x;  // 64 threads
  qsr[t]    = qs[(size_t)g*128 + t];
  qsr[64+t] = qs[(size_t)g*128 + 64 + t];
  __syncthreads();
  float acc = b1[t];
  for (int k=0; k<128; k++) acc += qsr[k]*W1[k*64+t];
  yy[t] = fmaxf(acc, 0.f);
  __syncthreads();
  if (t < 12){
    float a2 = b2[t];
    for (int k=0; k<64; k++) a2 += yy[k]*W2[k*12+t];
    outy[(size_t)g*12 + t] = a2;
  }
}

extern "C" void kernel_launch(void* const* d_in, const int* in_sizes, int n_in,
                              void* d_out, int out_size, void* d_ws, size_t ws_size,
                              hipStream_t stream){
  const float* x    = (const float*)d_in[0];
  const int*   ei   = (const int*)d_in[1];
  const int*   batch= (const int*)d_in[2];
  const float* W0   = (const float*)d_in[3];
  const float* b0   = (const float*)d_in[4];
  const float* Wc   = (const float*)d_in[5];
  const float* bc   = (const float*)d_in[6];
  const float* Wih  = (const float*)d_in[7];
  const float* Whh  = (const float*)d_in[8];
  const float* bih  = (const float*)d_in[9];
  const float* bhh  = (const float*)d_in[10];
  const float* W1   = (const float*)d_in[11];
  const float* b1   = (const float*)d_in[12];
  const float* W2   = (const float*)d_in[13];
  const float* b2   = (const float*)d_in[14];
  float* yout = (float*)d_out;

  const int N = in_sizes[0]/15;
  const int E = in_sizes[1]/2;
  const int B = out_size/12;
  const int* row = ei;       // sources
  const int* col = ei + E;   // targets

  char* ws = (char*)d_ws;
  size_t off = 0;
  auto alloc = [&](size_t bytes)->void*{
    void* p = ws + off; off = (off + bytes + 255) & ~(size_t)255; return p;
  };
  int*   deg     = (int*)  alloc((size_t)N*4);
  int*   fill    = (int*)  alloc((size_t)N*4);
  int*   rowptr  = (int*)  alloc((size_t)(N+1)*4);
  int*   partial = (int*)  alloc((size_t)N*4);
  int*   bsum    = (int*)  alloc(4096);
  int*   csr     = (int*)  alloc((size_t)E*4);
  float* dinv    = (float*)alloc((size_t)N*4);
  float* nodef   = (float*)alloc((size_t)N*ND*4);
  float* gbuf    = (float*)alloc((size_t)N*ND*4);
  int*   goff    = (int*)  alloc((size_t)(B+1)*4);
  float* hl      = (float*)alloc((size_t)B*64*4);
  float* cl      = (float*)alloc((size_t)B*64*4);
  float* qs      = (float*)alloc((size_t)B*128*4);
  (void)ws_size; (void)n_in;

  hipMemsetAsync(deg,  0, (size_t)N*4, stream);
  hipMemsetAsync(fill, 0, (size_t)N*4, stream);
  hipMemsetAsync(hl,   0, (size_t)B*64*4, stream);
  hipMemsetAsync(cl,   0, (size_t)B*64*4, stream);
  hipMemsetAsync(qs,   0, (size_t)B*128*4, stream);

  k_degree<<<(E+255)/256, 256, 0, stream>>>(col, deg, E);
  k_dinv  <<<(N+255)/256, 256, 0, stream>>>(deg, dinv, N);
  int nb = (N + SCAN_BLK - 1)/SCAN_BLK;
  k_scan1<<<nb, SCAN_BLK, 0, stream>>>(deg, partial, bsum, N);
  k_scan2<<<1, 64, 0, stream>>>(bsum, nb);
  k_scan3<<<nb, SCAN_BLK, 0, stream>>>(partial, bsum, rowptr, N);
  k_fill <<<(E+255)/256, 256, 0, stream>>>(row, col, rowptr, fill, csr, E);

  k_input<<<(N+3)/4, 256, 0, stream>>>(x, W0, b0, nodef, N);
  for (int s6=0; s6<6; ++s6){
    k_transform<<<(N+15)/16, 256, 0, stream>>>(nodef, Wc, dinv, gbuf, N);
    k_gather   <<<(N+3)/4,   256, 0, stream>>>(gbuf, rowptr, csr, dinv, bc, nodef, N);
  }

  k_goff<<<(N+255)/256, 256, 0, stream>>>(batch, goff, N, B);
  for (int s6=0; s6<6; ++s6){
    k_lstm<<<B/8, 256, 0, stream>>>(Wih, Whh, bih, bhh, qs, hl, cl);
    k_attn<<<B,   256, 0, stream>>>(nodef, goff, hl, qs);
  }
  k_final<<<B, 64, 0, stream>>>(qs, W1, b1, W2, b2, yout);
}

// Round 2
// 1510.384 us; speedup vs baseline: 1.0710x; 1.0710x over previous
//
#include <hip/hip_runtime.h>
#include <hip/hip_fp16.h>
#include <math.h>

#define ND 64
constexpr int SCAN_BLK = 1024;

__device__ __forceinline__ float sigmoidf_(float x){ return 1.f/(1.f+__expf(-x)); }

// ---------------- CSR build ----------------
__global__ void k_degree(const int* __restrict__ col, int* __restrict__ deg, int E){
  int i = blockIdx.x*blockDim.x + threadIdx.x;
  if (i < E) atomicAdd(&deg[col[i]], 1);
}

__global__ void k_dinv(const int* __restrict__ deg, float* __restrict__ dinv, int N){
  int i = blockIdx.x*blockDim.x + threadIdx.x;
  if (i < N) dinv[i] = rsqrtf((float)(deg[i] + 1));   // +1 = self loop
}

__global__ void k_scan1(const int* __restrict__ cnt, int* __restrict__ partial,
                        int* __restrict__ bsum, int n){
  __shared__ int tmp[SCAN_BLK];
  int i = blockIdx.x*SCAN_BLK + threadIdx.x;
  int v = (i<n) ? cnt[i] : 0;
  tmp[threadIdx.x] = v; __syncthreads();
  for (int off=1; off<SCAN_BLK; off<<=1){
    int t = (threadIdx.x>=off) ? tmp[threadIdx.x-off] : 0;
    __syncthreads();
    tmp[threadIdx.x] += t;
    __syncthreads();
  }
  if (i<n) partial[i] = tmp[threadIdx.x];
  if (threadIdx.x==SCAN_BLK-1) bsum[blockIdx.x] = tmp[threadIdx.x];
}

__global__ void k_scan2(int* bsum, int nb){
  if (threadIdx.x==0 && blockIdx.x==0){
    int acc=0;
    for (int b=0;b<nb;b++){ int v=bsum[b]; bsum[b]=acc; acc+=v; }
  }
}

// rowptr[c] = start of node c (rowptr[0]=0). After k_fill's atomicAdd pass,
// rowptr[c] = end of node c, so gather uses [rowptr[c-1], rowptr[c]).
__global__ void k_scan3(const int* __restrict__ partial, const int* __restrict__ bsum,
                        int* __restrict__ rowptr, int n){
  int i = blockIdx.x*SCAN_BLK + threadIdx.x;
  if (i<n){
    int inc = partial[i] + bsum[blockIdx.x];   // inclusive scan = start of node i+1
    if (i < n-1) rowptr[i+1] = inc;
    if (i==0) rowptr[0] = 0;
  }
}

__global__ void k_fill(const int* __restrict__ row, const int* __restrict__ col,
                       int* __restrict__ rowptr, int* __restrict__ csr, int E){
  int i = blockIdx.x*blockDim.x + threadIdx.x;
  if (i < E){
    int c = col[i];
    int pos = atomicAdd(&rowptr[c], 1);   // rowptr doubles as the fill cursor
    csr[pos] = row[i];
  }
}

// ---------------- input MLP: out = relu(x @ W0 + b0) ----------------
__global__ void k_input(const float* __restrict__ x, const float* __restrict__ W0,
                        const float* __restrict__ b0, float* __restrict__ out, int N){
  __shared__ float w0s[15*ND];
  __shared__ float b0s[ND];
  int tid = threadIdx.x;
  for (int i=tid; i<15*ND; i+=256) w0s[i] = W0[i];
  if (tid < ND) b0s[tid] = b0[tid];
  __syncthreads();
  int node = blockIdx.x*4 + (tid>>6);
  int f = tid & 63;
  if (node < N){
    float acc = b0s[f];
    const float* xr = x + (size_t)node*15;
    #pragma unroll
    for (int k=0;k<15;k++) acc += xr[k]*w0s[k*ND+f];
    out[(size_t)node*ND+f] = fmaxf(acc, 0.f);
  }
}

// ---------------- g16 = fp16( dinv * (out @ Wc) ) ----------------
__global__ void k_transform(const float* __restrict__ out, const float* __restrict__ Wc,
                            const float* __restrict__ dinv, __half* __restrict__ g, int N){
  __shared__ float wcs[ND*ND];
  __shared__ float xs[16][ND];
  int tid = threadIdx.x;
  for (int i=tid; i<ND*ND; i+=256) wcs[i] = Wc[i];
  int nb = blockIdx.x*16;
  for (int i=tid; i<16*ND; i+=256){
    int n = i>>6, k = i&63; int node = nb+n;
    xs[n][k] = (node<N) ? out[(size_t)node*ND+k] : 0.f;
  }
  __syncthreads();
  int f = tid&63, nq = tid>>6;
  float acc0=0.f, acc1=0.f, acc2=0.f, acc3=0.f;
  #pragma unroll 16
  for (int k=0;k<ND;k++){
    float w = wcs[k*ND+f];
    acc0 += w*xs[nq*4+0][k];
    acc1 += w*xs[nq*4+1][k];
    acc2 += w*xs[nq*4+2][k];
    acc3 += w*xs[nq*4+3][k];
  }
  int n0 = nb + nq*4;
  if (n0+0 < N) g[(size_t)(n0+0)*ND+f] = __float2half_rn(dinv[n0+0]*acc0);
  if (n0+1 < N) g[(size_t)(n0+1)*ND+f] = __float2half_rn(dinv[n0+1]*acc1);
  if (n0+2 < N) g[(size_t)(n0+2)*ND+f] = __float2half_rn(dinv[n0+2]*acc2);
  if (n0+3 < N) g[(size_t)(n0+3)*ND+f] = __float2half_rn(dinv[n0+3]*acc3);
}

// ---------------- out[dst] = relu(dinv[dst]*(sum g[src] + g[dst]) + bc) ----------------
__global__ void k_gather(const __half* __restrict__ g, const int* __restrict__ rowptr,
                         const int* __restrict__ csr, const float* __restrict__ dinv,
                         const float* __restrict__ bc, float* __restrict__ out, int N){
  int tid = threadIdx.x;
  int node = blockIdx.x*4 + (tid>>6);
  if (node >= N) return;
  int lane = tid & 63;
  int s = (node==0) ? 0 : rowptr[node-1];
  int e = rowptr[node];
  float a0 = __half2float(g[(size_t)node*ND+lane]);   // self loop
  float a1=0.f, a2=0.f, a3=0.f, a4=0.f, a5=0.f, a6=0.f, a7=0.f;
  int i = s;
  for (; i+8 <= e; i += 8){
    int s0=csr[i],   s1=csr[i+1], s2=csr[i+2], s3=csr[i+3];
    int s4=csr[i+4], s5=csr[i+5], s6=csr[i+6], s7=csr[i+7];
    a0 += __half2float(g[(size_t)s0*ND+lane]);
    a1 += __half2float(g[(size_t)s1*ND+lane]);
    a2 += __half2float(g[(size_t)s2*ND+lane]);
    a3 += __half2float(g[(size_t)s3*ND+lane]);
    a4 += __half2float(g[(size_t)s4*ND+lane]);
    a5 += __half2float(g[(size_t)s5*ND+lane]);
    a6 += __half2float(g[(size_t)s6*ND+lane]);
    a7 += __half2float(g[(size_t)s7*ND+lane]);
  }
  for (; i<e; ++i) a0 += __half2float(g[(size_t)csr[i]*ND+lane]);
  float r = dinv[node]*(((a0+a1)+(a2+a3)) + ((a4+a5)+(a6+a7))) + bc[lane];
  out[(size_t)node*ND+lane] = fmaxf(r, 0.f);
}

// ---------------- per-graph contiguous ranges (batch is sorted) ----------------
__global__ void k_goff(const int* __restrict__ batch, int* __restrict__ goff, int N, int B){
  int i = blockIdx.x*blockDim.x + threadIdx.x;
  if (i >= N) return;
  int b = batch[i];
  if (i == 0){ for (int g2=0; g2<=b; ++g2) goff[g2]=0; }
  else {
    int bp = batch[i-1];
    for (int g2=bp+1; g2<=b; ++g2) goff[g2]=i;
  }
  if (i == N-1){ for (int g2=b+1; g2<=B; ++g2) goff[g2]=N; }
}

// ---------------- LSTM step (8 graphs per block) ----------------
__global__ void k_lstm(const float* __restrict__ Wih, const float* __restrict__ Whh,
                       const float* __restrict__ bih, const float* __restrict__ bhh,
                       float* __restrict__ qs, float* __restrict__ hl, float* __restrict__ cl){
  __shared__ float qsr[8][128];
  __shared__ float hlr[8][64];
  __shared__ float gat[8][256];
  int tid = threadIdx.x;
  int g0 = blockIdx.x*8;
  for (int i=tid; i<8*128; i+=256){ int gg=i>>7, k=i&127; qsr[gg][k] = qs[(size_t)(g0+gg)*128+k]; }
  for (int i=tid; i<8*64;  i+=256){ int gg=i>>6, k=i&63;  hlr[gg][k] = hl[(size_t)(g0+gg)*64+k]; }
  __syncthreads();
  int j = tid;  // gate index 0..255
  float bb = bih[j] + bhh[j];
  float acc[8];
  #pragma unroll
  for (int gg=0; gg<8; gg++) acc[gg] = bb;
  const float* wr = Wih + (size_t)j*128;
  for (int k=0; k<128; k++){
    float w = wr[k];
    #pragma unroll
    for (int gg=0; gg<8; gg++) acc[gg] += w*qsr[gg][k];
  }
  const float* wr2 = Whh + (size_t)j*64;
  for (int k=0; k<64; k++){
    float w = wr2[k];
    #pragma unroll
    for (int gg=0; gg<8; gg++) acc[gg] += w*hlr[gg][k];
  }
  #pragma unroll
  for (int gg=0; gg<8; gg++) gat[gg][j] = acc[gg];
  __syncthreads();
  #pragma unroll
  for (int it=0; it<2; ++it){
    int idx = it*256 + tid;
    int gg = idx>>6, d = idx&63;
    int graph = g0+gg;
    float ig = sigmoidf_(gat[gg][d]);
    float fg = sigmoidf_(gat[gg][64+d]);
    float gv = tanhf(gat[gg][128+d]);
    float og = sigmoidf_(gat[gg][192+d]);
    float c = fg*cl[(size_t)graph*64+d] + ig*gv;
    float h = og*tanhf(c);
    cl[(size_t)graph*64+d] = c;
    hl[(size_t)graph*64+d] = h;
    qs[(size_t)graph*128+d] = h;   // q part of q_star
  }
}

// ---------------- attention pooling, block per graph ----------------
__global__ void k_attn(const float* __restrict__ out, const int* __restrict__ goff,
                       const float* __restrict__ hl, float* __restrict__ qs){
  __shared__ float redw[4];
  __shared__ float redr[4][64];
  int g = blockIdx.x;
  int tid = threadIdx.x, lane = tid&63, wv = tid>>6;
  int s = goff[g], e = goff[g+1];
  float q = hl[(size_t)g*64+lane];
  // pass A: global max of e_n = dot(out[n], q)
  float mx = -1e30f;
  for (int n=s+wv; n<e; n+=4){
    float p = out[(size_t)n*64+lane]*q;
    #pragma unroll
    for (int off=32; off>=1; off>>=1) p += __shfl_xor(p, off, 64);
    mx = fmaxf(mx, p);
  }
  if (lane==0) redw[wv] = mx;
  __syncthreads();
  float m = fmaxf(fmaxf(redw[0],redw[1]), fmaxf(redw[2],redw[3]));
  __syncthreads();
  // pass B: denom and weighted sum in one sweep
  float denom=0.f, racc=0.f;
  for (int n=s+wv; n<e; n+=4){
    float v = out[(size_t)n*64+lane];
    float p = v*q;
    #pragma unroll
    for (int off=32; off>=1; off>>=1) p += __shfl_xor(p, off, 64);
    float w = __expf(p - m);
    denom += w;
    racc += w*v;
  }
  if (lane==0) redw[wv] = denom;
  redr[wv][lane] = racc;
  __syncthreads();
  if (wv==0){
    float dtot = redw[0]+redw[1]+redw[2]+redw[3];
    float rs = redr[0][lane]+redr[1][lane]+redr[2][lane]+redr[3][lane];
    qs[(size_t)g*128+64+lane] = (dtot > 0.f) ? rs/dtot : 0.f;
  }
}

// ---------------- final MLP ----------------
__global__ void k_final(const float* __restrict__ qs, const float* __restrict__ W1,
                        const float* __restrict__ b1, const float* __restrict__ W2,
                        const float* __restrict__ b2, float* __restrict__ outy){
  __shared__ float qsr[128];
  __shared__ float yy[64];
  int g = blockIdx.x; int t = threadIdx.x;  // 64 threads
  qsr[t]    = qs[(size_t)g*128 + t];
  qsr[64+t] = qs[(size_t)g*128 + 64 + t];
  __syncthreads();
  float acc = b1[t];
  for (int k=0; k<128; k++) acc += qsr[k]*W1[k*64+t];
  yy[t] = fmaxf(acc, 0.f);
  __syncthreads();
  if (t < 12){
    float a2 = b2[t];
    for (int k=0; k<64; k++) a2 += yy[k]*W2[k*12+t];
    outy[(size_t)g*12 + t] = a2;
  }
}

extern "C" void kernel_launch(void* const* d_in, const int* in_sizes, int n_in,
                              void* d_out, int out_size, void* d_ws, size_t ws_size,
                              hipStream_t stream){
  const float* x    = (const float*)d_in[0];
  const int*   ei   = (const int*)d_in[1];
  const int*   batch= (const int*)d_in[2];
  const float* W0   = (const float*)d_in[3];
  const float* b0   = (const float*)d_in[4];
  const float* Wc   = (const float*)d_in[5];
  const float* bc   = (const float*)d_in[6];
  const float* Wih  = (const float*)d_in[7];
  const float* Whh  = (const float*)d_in[8];
  const float* bih  = (const float*)d_in[9];
  const float* bhh  = (const float*)d_in[10];
  const float* W1   = (const float*)d_in[11];
  const float* b1   = (const float*)d_in[12];
  const float* W2   = (const float*)d_in[13];
  const float* b2   = (const float*)d_in[14];
  float* yout = (float*)d_out;

  const int N = in_sizes[0]/15;
  const int E = in_sizes[1]/2;
  const int B = out_size/12;
  const int* row = ei;       // sources
  const int* col = ei + E;   // targets

  char* ws = (char*)d_ws;
  size_t off = 0;
  auto alloc = [&](size_t bytes)->void*{
    void* p = ws + off; off = (off + bytes + 255) & ~(size_t)255; return p;
  };
  int*    deg     = (int*)   alloc((size_t)N*4);
  int*    rowptr  = (int*)   alloc((size_t)(N+1)*4);
  int*    partial = (int*)   alloc((size_t)N*4);
  int*    bsum    = (int*)   alloc(4096);
  int*    csr     = (int*)   alloc((size_t)E*4);
  float*  dinv    = (float*) alloc((size_t)N*4);
  float*  nodef   = (float*) alloc((size_t)N*ND*4);
  __half* gbuf    = (__half*)alloc((size_t)N*ND*2);
  int*    goff    = (int*)   alloc((size_t)(B+1)*4);
  float*  hl      = (float*) alloc((size_t)B*64*4);
  float*  cl      = (float*) alloc((size_t)B*64*4);
  float*  qs      = (float*) alloc((size_t)B*128*4);
  (void)ws_size; (void)n_in;

  hipMemsetAsync(deg,  0, (size_t)N*4, stream);
  hipMemsetAsync(hl,   0, (size_t)B*64*4, stream);
  hipMemsetAsync(cl,   0, (size_t)B*64*4, stream);
  hipMemsetAsync(qs,   0, (size_t)B*128*4, stream);

  k_degree<<<(E+255)/256, 256, 0, stream>>>(col, deg, E);
  k_dinv  <<<(N+255)/256, 256, 0, stream>>>(deg, dinv, N);
  int nb = (N + SCAN_BLK - 1)/SCAN_BLK;
  k_scan1<<<nb, SCAN_BLK, 0, stream>>>(deg, partial, bsum, N);
  k_scan2<<<1, 64, 0, stream>>>(bsum, nb);
  k_scan3<<<nb, SCAN_BLK, 0, stream>>>(partial, bsum, rowptr, N);
  k_fill <<<(E+255)/256, 256, 0, stream>>>(row, col, rowptr, csr, E);

  k_input<<<(N+3)/4, 256, 0, stream>>>(x, W0, b0, nodef, N);
  for (int s6=0; s6<6; ++s6){
    k_transform<<<(N+15)/16, 256, 0, stream>>>(nodef, Wc, dinv, gbuf, N);
    k_gather   <<<(N+3)/4,   256, 0, stream>>>(gbuf, rowptr, csr, dinv, bc, nodef, N);
  }

  k_goff<<<(N+255)/256, 256, 0, stream>>>(batch, goff, N, B);
  for (int s6=0; s6<6; ++s6){
    k_lstm<<<B/8, 256, 0, stream>>>(Wih, Whh, bih, bhh, qs, hl, cl);
    k_attn<<<B,   256, 0, stream>>>(nodef, goff, hl, qs);
  }
  k_final<<<B, 64, 0, stream>>>(qs, W1, b1, W2, b2, yout);
}